// Round 9
// baseline (21.522 us; speedup 1.0000x reference)
//
#include <hip/hip_runtime.h>
#include <math.h>

#define BB 128
#define CC 64
#define EPSF 1e-6f

#define NB 8                  // local bins, width 2.0 over [4,20), clamped
#define BIN_LO 4.0f
#define BIN_INV 0.5f
#define FIX1 256.0f           // fixed-point scale for sum(dt)
#define FIX2 16.0f            // fixed-point scale for sum(dt^2)
#define DENOM 508032.0        // B*(C-1)^2

#define NBLK 512              // 64 ic-chunks (2 dp rows) x 8 sc-chunks (512 dt pairs)

// ws layout: double partial[512] @0 ; u32 tag[512] @4096 ; u32 epoch @6144
// Never pre-zeroed: epoch-tag handshake valid for any initial bits
// (virgin zeros, 0xAA poison, stale tags == E; fresh tags == E+1).
#define WS_PART(ws)  ((double*)(ws))
#define WS_TAG(ws)   ((unsigned int*)((char*)(ws) + 4096))
#define WS_EPOCH(ws) ((unsigned int*)((char*)(ws) + 6144))

__global__ void __launch_bounds__(256) fused_kernel(const float* __restrict__ yp,
                                                    const float* __restrict__ yt,
                                                    void* __restrict__ ws,
                                                    float* __restrict__ out) {
    // [k4][row] float4 tiles; +1 float4 pad -> per-lane b128 reads conflict-free.
    __shared__ float4 ypT4[16][BB + 1];
    __shared__ float4 ytT4[16][CC + 1];
    __shared__ unsigned int hcnt[NB];
    __shared__ unsigned int hfx1[NB];
    __shared__ unsigned int hfx2[NB];
    __shared__ float dps[256];
    __shared__ double red[4];

    int tid  = threadIdx.x;
    int lane = tid & 63;
    int w    = tid >> 6;            // wave 0..3
    int bid  = blockIdx.x;
    int ic   = bid >> 3;            // dp chunk 0..63 (2 rows each)
    int sc   = bid & 7;             // dt chunk 0..7  (512 pairs each)

    if (tid < NB) { hcnt[tid] = 0u; hfx1[tid] = 0u; hfx2[tid] = 0u; }

    // ---- stage yp, yt as float4 tiles (coalesced load + ds_write_b128) ----
    const float4* yp4 = (const float4*)yp;
#pragma unroll
    for (int it = 0; it < (BB * CC / 4) / 256; ++it) {      // 8 iters
        int idx4 = it * 256 + tid;
        ypT4[idx4 & 15][idx4 >> 4] = yp4[idx4];
    }
    const float4* yt4 = (const float4*)yt;
#pragma unroll
    for (int it = 0; it < (CC * CC / 4) / 256; ++it) {      // 4 iters
        int idx4 = it * 256 + tid;
        ytT4[idx4 & 15][idx4 >> 4] = yt4[idx4];
    }
    __syncthreads();

    // ---- wave-specialized distance pass (register sharing of per-lane rows) ----
    if (w >= 2) {
        // waves 2,3: dp -- thread owns col jj, computes BOTH i-rows off one vj read
        int jj = (w - 2) * 64 + lane;
        int i0 = ic * 2;
        float s0 = 0.f, s1 = 0.f;
#pragma unroll
        for (int k4 = 0; k4 < 16; ++k4) {
            float4 vj  = ypT4[k4][jj];        // per-lane b128, conflict-free
            float4 bi0 = ypT4[k4][i0];        // broadcast
            float4 bi1 = ypT4[k4][i0 + 1];    // broadcast
            float a0 = vj.x - bi0.x + EPSF, a1 = vj.y - bi0.y + EPSF;
            float a2 = vj.z - bi0.z + EPSF, a3 = vj.w - bi0.w + EPSF;
            s0 = fmaf(a0, a0, s0); s0 = fmaf(a1, a1, s0);
            s0 = fmaf(a2, a2, s0); s0 = fmaf(a3, a3, s0);
            float b0 = vj.x - bi1.x + EPSF, b1 = vj.y - bi1.y + EPSF;
            float b2 = vj.z - bi1.z + EPSF, b3 = vj.w - bi1.w + EPSF;
            s1 = fmaf(b0, b0, s1); s1 = fmaf(b1, b1, s1);
            s1 = fmaf(b2, b2, s1); s1 = fmaf(b3, b3, s1);
        }
        dps[jj]       = sqrtf(s0);
        dps[128 + jj] = sqrtf(s1);
    } else {
        // waves 0,1: dt -- thread owns row d=lane, computes 4 c-rows off one vd read
        int c0 = sc * 8 + w * 4;
        float t0 = 0.f, t1 = 0.f, t2 = 0.f, t3 = 0.f;
#pragma unroll
        for (int k4 = 0; k4 < 16; ++k4) {
            float4 vd  = ytT4[k4][lane];      // per-lane b128, conflict-free
            float4 c0v = ytT4[k4][c0];        // broadcasts
            float4 c1v = ytT4[k4][c0 + 1];
            float4 c2v = ytT4[k4][c0 + 2];
            float4 c3v = ytT4[k4][c0 + 3];
            float e0, e1, e2, e3;
            e0 = vd.x - c0v.x + EPSF; e1 = vd.y - c0v.y + EPSF;
            e2 = vd.z - c0v.z + EPSF; e3 = vd.w - c0v.w + EPSF;
            t0 = fmaf(e0, e0, t0); t0 = fmaf(e1, e1, t0);
            t0 = fmaf(e2, e2, t0); t0 = fmaf(e3, e3, t0);
            e0 = vd.x - c1v.x + EPSF; e1 = vd.y - c1v.y + EPSF;
            e2 = vd.z - c1v.z + EPSF; e3 = vd.w - c1v.w + EPSF;
            t1 = fmaf(e0, e0, t1); t1 = fmaf(e1, e1, t1);
            t1 = fmaf(e2, e2, t1); t1 = fmaf(e3, e3, t1);
            e0 = vd.x - c2v.x + EPSF; e1 = vd.y - c2v.y + EPSF;
            e2 = vd.z - c2v.z + EPSF; e3 = vd.w - c2v.w + EPSF;
            t2 = fmaf(e0, e0, t2); t2 = fmaf(e1, e1, t2);
            t2 = fmaf(e2, e2, t2); t2 = fmaf(e3, e3, t2);
            e0 = vd.x - c3v.x + EPSF; e1 = vd.y - c3v.y + EPSF;
            e2 = vd.z - c3v.z + EPSF; e3 = vd.w - c3v.w + EPSF;
            t3 = fmaf(e0, e0, t3); t3 = fmaf(e1, e1, t3);
            t3 = fmaf(e2, e2, t3); t3 = fmaf(e3, e3, t3);
        }
        float vt[4] = { sqrtf(t0), sqrtf(t1), sqrtf(t2), sqrtf(t3) };
#pragma unroll
        for (int m = 0; m < 4; ++m) {
            if (lane != c0 + m) {             // skip diagonal
                float v = vt[m];
                int b = (int)((v - BIN_LO) * BIN_INV);
                b = b < 0 ? 0 : (b > NB - 1 ? NB - 1 : b);
                atomicAdd(&hcnt[b], 1u);
                atomicAdd(&hfx1[b], (unsigned int)(v * FIX1 + 0.5f));
                atomicAdd(&hfx2[b], (unsigned int)(v * v * FIX2 + 0.5f));
            }
        }
    }
    __syncthreads();

    // ---- softplus: thread owns bin b=tid&7, entry group q=tid>>3 (8 entries) ----
    int b = tid & 7;
    int q = tid >> 3;
    float cnt  = (float)hcnt[b];
    float sum  = (float)hfx1[b] * (1.f / FIX1);
    float sum2 = (float)hfx2[b] * (1.f / FIX2);
    float mean = cnt > 0.f ? sum / cnt : 0.f;
    float m2c  = sum2 - mean * sum;      // sum of (dt - mean)^2 in bin
    float partS = 0.f, partC = 0.f;
#pragma unroll
    for (int p = 0; p < 8; ++p) {
        float x = dps[q * 8 + p] - mean;
        float ee = __expf(-fabsf(x));
        float r  = 1.f / (1.f + ee);
        partS += fmaxf(x, 0.f) + __logf(1.f + ee);
        partC += ee * r * r;             // softplus''(x) summed
    }
    double local = (double)(cnt * partS + 0.5f * m2c * partC);
    if (tid < NB) local -= 256.0 * (double)sum;   // term2: (dp pairs in block) * chunk dt-sum

    for (int off = 32; off > 0; off >>= 1)
        local += __shfl_down(local, off);
    if (lane == 0) red[w] = local;
    __syncthreads();

    // ---- epoch-tagged partial publish (no pre-initialized state needed) ----
    unsigned int E = __hip_atomic_load(WS_EPOCH(ws), __ATOMIC_RELAXED,
                                       __HIP_MEMORY_SCOPE_AGENT);
    if (tid == 0) {
        double s = red[0] + red[1] + red[2] + red[3];
        __hip_atomic_store(&WS_PART(ws)[bid], s, __ATOMIC_RELAXED,
                           __HIP_MEMORY_SCOPE_AGENT);
        __hip_atomic_store(&WS_TAG(ws)[bid], E + 1u, __ATOMIC_RELEASE,
                           __HIP_MEMORY_SCOPE_AGENT);
    }

    // ---- finalizer: block 511 spins for all 512 fresh tags, sums, stores ----
    if (bid == NBLK - 1) {
        unsigned int want = E + 1u;
        double acc2 = 0.0;
        for (int slot = tid; slot < NBLK; slot += 256) {
            while (__hip_atomic_load(&WS_TAG(ws)[slot], __ATOMIC_ACQUIRE,
                                     __HIP_MEMORY_SCOPE_AGENT) != want)
                __builtin_amdgcn_s_sleep(2);
            acc2 += __hip_atomic_load(&WS_PART(ws)[slot], __ATOMIC_RELAXED,
                                      __HIP_MEMORY_SCOPE_AGENT);
        }
        for (int off = 32; off > 0; off >>= 1)
            acc2 += __shfl_down(acc2, off);
        __syncthreads();                    // before reusing red[]
        if (lane == 0) red[w] = acc2;
        __syncthreads();
        if (tid == 0) {
            double total = red[0] + red[1] + red[2] + red[3];
            out[0] = (float)(total / DENOM);
            __hip_atomic_store(WS_EPOCH(ws), E + 1u, __ATOMIC_RELEASE,
                               __HIP_MEMORY_SCOPE_AGENT);
        }
    }
}

extern "C" void kernel_launch(void* const* d_in, const int* in_sizes, int n_in,
                              void* d_out, int out_size, void* d_ws, size_t ws_size,
                              hipStream_t stream) {
    const float* yp = (const float*)d_in[0];
    const float* yt = (const float*)d_in[1];
    fused_kernel<<<NBLK, 256, 0, stream>>>(yp, yt, d_ws, (float*)d_out);
}

// Round 10
// 16.851 us; speedup vs baseline: 1.2772x; 1.2772x over previous
//
#include <hip/hip_runtime.h>
#include <math.h>

#define BB 128
#define CC 64
#define EPSF 1e-6f

#define NB 16                 // local bins, width 1.0 over [4,20), clamped
#define BIN_LO 4.0f
#define FIX1 256.0f           // fixed-point scale for sum(dt)
#define FIX2 16.0f            // fixed-point scale for sum(dt^2)
#define DENOM 508032.0        // B*(C-1)^2

#define NBLK 512              // 64 ic-chunks (2 dp rows) x 8 sc-chunks (512 dt pairs)

// ws layout: double partial[512] @0 ; u32 tag[512] @4096 ; u32 epoch @6144
// Never pre-zeroed: epoch-tag handshake valid for any initial bits
// (virgin zeros, 0xAA poison, stale tags == E; fresh tags == E+1).
#define WS_PART(ws)  ((double*)(ws))
#define WS_TAG(ws)   ((unsigned int*)((char*)(ws) + 4096))
#define WS_EPOCH(ws) ((unsigned int*)((char*)(ws) + 6144))

// R9 post-mortem note: wave-specializing dp/dt and shrinking to 8 bins
// REGRESSED (17.1 -> 21.5us): same-address LDS atomic contention on 24 words
// + loss of cross-wave latency overlap. This is the R8 structure (best: 17.07us).
__global__ void __launch_bounds__(256) fused_kernel(const float* __restrict__ yp,
                                                    const float* __restrict__ yt,
                                                    void* __restrict__ ws,
                                                    float* __restrict__ out) {
    // [k4][row] float4 tiles; +1 float4 pad -> row stride 516 dwords == 4 mod 32:
    // per-lane b128 reads hit 8 lanes/bank = the b128 BW floor (conflict-free).
    __shared__ float4 ypT4[16][BB + 1];
    __shared__ float4 ytT4[16][CC + 1];
    __shared__ unsigned int hcnt[NB];
    __shared__ unsigned int hfx1[NB];
    __shared__ unsigned int hfx2[NB];
    __shared__ float dps[256];
    __shared__ double red[4];

    int tid  = threadIdx.x;
    int lane = tid & 63;
    int w    = tid >> 6;            // wave 0..3
    int bid  = blockIdx.x;
    int ic   = bid >> 3;            // dp chunk 0..63 (2 rows each)
    int sc   = bid & 7;             // dt chunk 0..7  (512 pairs each)

    if (tid < NB) { hcnt[tid] = 0u; hfx1[tid] = 0u; hfx2[tid] = 0u; }

    // ---- stage yp, yt as float4 tiles (1 coalesced load + 1 ds_write_b128 per iter) ----
    const float4* yp4 = (const float4*)yp;
#pragma unroll
    for (int it = 0; it < (BB * CC / 4) / 256; ++it) {      // 8 iters
        int idx4 = it * 256 + tid;
        ypT4[idx4 & 15][idx4 >> 4] = yp4[idx4];             // row = idx4>>4, k4 = idx4&15
    }
    const float4* yt4 = (const float4*)yt;
#pragma unroll
    for (int it = 0; it < (CC * CC / 4) / 256; ++it) {      // 4 iters
        int idx4 = it * 256 + tid;
        ytT4[idx4 & 15][idx4 >> 4] = yt4[idx4];
    }
    __syncthreads();

    // ---- fused distance pass: 1 dp entry + 2 dt entries per thread, 4 k per iter ----
    int i  = ic * 2 + (w >> 1);          // wave-uniform dp row
    int jj = (w & 1) * 64 + lane;        // dp col
    int c0 = sc * 8 + w * 2;             // wave-uniform dt rows c0, c0+1
    float s1 = 0.f, t0 = 0.f, t1 = 0.f;
#pragma unroll
    for (int k4 = 0; k4 < 16; ++k4) {
        float4 vj  = ypT4[k4][jj];       // per-lane b128, conflict-free
        float4 bi  = ypT4[k4][i];        // broadcast
        float4 vd  = ytT4[k4][lane];     // per-lane b128, conflict-free
        float4 bc0 = ytT4[k4][c0];       // broadcast
        float4 bc1 = ytT4[k4][c0 + 1];   // broadcast
        float d0 = vj.x - bi.x + EPSF, d1 = vj.y - bi.y + EPSF;
        float d2 = vj.z - bi.z + EPSF, d3 = vj.w - bi.w + EPSF;
        s1 = fmaf(d0, d0, s1); s1 = fmaf(d1, d1, s1);
        s1 = fmaf(d2, d2, s1); s1 = fmaf(d3, d3, s1);
        float e0 = vd.x - bc0.x + EPSF, e1 = vd.y - bc0.y + EPSF;
        float e2 = vd.z - bc0.z + EPSF, e3 = vd.w - bc0.w + EPSF;
        t0 = fmaf(e0, e0, t0); t0 = fmaf(e1, e1, t0);
        t0 = fmaf(e2, e2, t0); t0 = fmaf(e3, e3, t0);
        float f0 = vd.x - bc1.x + EPSF, f1 = vd.y - bc1.y + EPSF;
        float f2 = vd.z - bc1.z + EPSF, f3 = vd.w - bc1.w + EPSF;
        t1 = fmaf(f0, f0, t1); t1 = fmaf(f1, f1, t1);
        t1 = fmaf(f2, f2, t1); t1 = fmaf(f3, f3, t1);
    }
    dps[tid] = sqrtf(s1);
    float vt0 = sqrtf(t0), vt1 = sqrtf(t1);
    if (lane != c0) {
        int b = (int)(vt0 - BIN_LO);
        b = b < 0 ? 0 : (b > NB - 1 ? NB - 1 : b);
        atomicAdd(&hcnt[b], 1u);
        atomicAdd(&hfx1[b], (unsigned int)(vt0 * FIX1 + 0.5f));
        atomicAdd(&hfx2[b], (unsigned int)(vt0 * vt0 * FIX2 + 0.5f));
    }
    if (lane != c0 + 1) {
        int b = (int)(vt1 - BIN_LO);
        b = b < 0 ? 0 : (b > NB - 1 ? NB - 1 : b);
        atomicAdd(&hcnt[b], 1u);
        atomicAdd(&hfx1[b], (unsigned int)(vt1 * FIX1 + 0.5f));
        atomicAdd(&hfx2[b], (unsigned int)(vt1 * vt1 * FIX2 + 0.5f));
    }
    __syncthreads();

    // ---- softplus: thread owns bin b=tid&15, entry group q=tid>>4 (16 entries) ----
    int b = tid & 15;
    int q = tid >> 4;
    float cnt  = (float)hcnt[b];
    float sum  = (float)hfx1[b] * (1.f / FIX1);
    float sum2 = (float)hfx2[b] * (1.f / FIX2);
    float mean = cnt > 0.f ? sum / cnt : 0.f;
    float m2c  = sum2 - mean * sum;      // sum of (dt - mean)^2 in bin
    float partS = 0.f, partC = 0.f;
#pragma unroll
    for (int p = 0; p < 16; ++p) {
        float x = dps[q * 16 + p] - mean;
        float ee = __expf(-fabsf(x));
        float r  = 1.f / (1.f + ee);
        partS += fmaxf(x, 0.f) + __logf(1.f + ee);
        partC += ee * r * r;             // softplus''(x) summed
    }
    double local = (double)(cnt * partS + 0.5f * m2c * partC);
    if (tid < NB) local -= 256.0 * (double)sum;   // term2: (dp pairs in block) * chunk dt-sum

    for (int off = 32; off > 0; off >>= 1)
        local += __shfl_down(local, off);
    if (lane == 0) red[w] = local;
    __syncthreads();

    // ---- epoch-tagged partial publish (no pre-initialized state needed) ----
    unsigned int E = __hip_atomic_load(WS_EPOCH(ws), __ATOMIC_RELAXED,
                                       __HIP_MEMORY_SCOPE_AGENT);
    if (tid == 0) {
        double s = red[0] + red[1] + red[2] + red[3];
        __hip_atomic_store(&WS_PART(ws)[bid], s, __ATOMIC_RELAXED,
                           __HIP_MEMORY_SCOPE_AGENT);
        __hip_atomic_store(&WS_TAG(ws)[bid], E + 1u, __ATOMIC_RELEASE,
                           __HIP_MEMORY_SCOPE_AGENT);
    }

    // ---- finalizer: block 511 spins for all 512 fresh tags, sums, stores ----
    if (bid == NBLK - 1) {
        unsigned int want = E + 1u;
        double acc2 = 0.0;
        for (int slot = tid; slot < NBLK; slot += 256) {
            while (__hip_atomic_load(&WS_TAG(ws)[slot], __ATOMIC_ACQUIRE,
                                     __HIP_MEMORY_SCOPE_AGENT) != want)
                __builtin_amdgcn_s_sleep(2);
            acc2 += __hip_atomic_load(&WS_PART(ws)[slot], __ATOMIC_RELAXED,
                                      __HIP_MEMORY_SCOPE_AGENT);
        }
        for (int off = 32; off > 0; off >>= 1)
            acc2 += __shfl_down(acc2, off);
        __syncthreads();                    // before reusing red[]
        if (lane == 0) red[w] = acc2;
        __syncthreads();
        if (tid == 0) {
            double total = red[0] + red[1] + red[2] + red[3];
            out[0] = (float)(total / DENOM);
            __hip_atomic_store(WS_EPOCH(ws), E + 1u, __ATOMIC_RELEASE,
                               __HIP_MEMORY_SCOPE_AGENT);
        }
    }
}

extern "C" void kernel_launch(void* const* d_in, const int* in_sizes, int n_in,
                              void* d_out, int out_size, void* d_ws, size_t ws_size,
                              hipStream_t stream) {
    const float* yp = (const float*)d_in[0];
    const float* yt = (const float*)d_in[1];
    fused_kernel<<<NBLK, 256, 0, stream>>>(yp, yt, d_ws, (float*)d_out);
}